// Round 2
// baseline (575.926 us; speedup 1.0000x reference)
//
#include <hip/hip_runtime.h>
#include <hip/hip_bf16.h>
#include <stdint.h>

#define NCTX 576
#define MLAT 64
#define SEQ 640
#define DMODEL 1024
#define NH 16
#define DHEAD 64
#define INNER_ 1024
#define KV_W 2048

typedef float f32x4 __attribute__((ext_vector_type(4)));
typedef __bf16 bf16x8 __attribute__((ext_vector_type(8)));
typedef unsigned short u16;
typedef unsigned int u32;
typedef unsigned long long u64;

typedef __attribute__((address_space(1))) u32 as1_u32;
typedef __attribute__((address_space(3))) u32 as3_u32;

__device__ __forceinline__ u16 f2bf(float f) {
    u32 u = __builtin_bit_cast(u32, f);
    u32 r = (u + 0x7fffu + ((u >> 16) & 1u)) >> 16;
    return (u16)r;
}

// T1: bijective XCD swizzle (m204). Maps linear wg id -> xcd-contiguous chunks.
__device__ __forceinline__ int xcd_swizzle(int orig, int nwg) {
    int q = nwg >> 3, r = nwg & 7;
    int xcd = orig & 7, loc = orig >> 3;
    return (xcd < r ? xcd * (q + 1) : r * (q + 1) + (xcd - r) * q) + loc;
}

// ---------------- weight transpose + cast: dst[n][k] = bf16(src[k][n]) ----------------
__global__ __launch_bounds__(256) void transpose_cast(const float* __restrict__ src,
                                                      u16* __restrict__ dst, int K, int N) {
    __shared__ float tile[64][65];
    int k0 = blockIdx.y * 64, n0 = blockIdx.x * 64;
    int tid = threadIdx.x;
#pragma unroll
    for (int i = 0; i < 4; ++i) {
        int idx = i * 256 + tid;
        int kk = idx >> 4;
        int nn = (idx & 15) << 2;
        float4 v = *(const float4*)(src + (u64)(k0 + kk) * N + n0 + nn);
        tile[kk][nn] = v.x; tile[kk][nn + 1] = v.y; tile[kk][nn + 2] = v.z; tile[kk][nn + 3] = v.w;
    }
    __syncthreads();
#pragma unroll
    for (int i = 0; i < 4; ++i) {
        int idx = i * 256 + tid;
        int nn = idx >> 4;
        int kk = (idx & 15) << 2;
        ushort4 o;
        o.x = f2bf(tile[kk][nn]);     o.y = f2bf(tile[kk + 1][nn]);
        o.z = f2bf(tile[kk + 2][nn]); o.w = f2bf(tile[kk + 3][nn]);
        *(ushort4*)(dst + (u64)(n0 + nn) * K + k0 + kk) = o;
    }
}

// ---------------- fused LayerNorm -> bf16 rows of concat(xn, ln) ----------------
__global__ __launch_bounds__(256) void ln_cast(const float* __restrict__ x,
                                               const float* __restrict__ lat,
                                               const float* __restrict__ gm, const float* __restrict__ bm,
                                               const float* __restrict__ gl, const float* __restrict__ bl,
                                               u16* __restrict__ out) {
    int row = blockIdx.x;              // chunk-local: bt*640 + s
    int bt = row / SEQ, s = row - bt * SEQ;
    const float *src, *g, *b;
    if (s < NCTX) { src = x + ((u64)bt * NCTX + s) * DMODEL; g = gm; b = bm; }
    else          { src = lat + ((u64)bt * MLAT + (s - NCTX)) * DMODEL; g = gl; b = bl; }
    int tid = threadIdx.x;
    float4 v = *(const float4*)(src + tid * 4);
    float sum = v.x + v.y + v.z + v.w;
    float sq  = v.x * v.x + v.y * v.y + v.z * v.z + v.w * v.w;
#pragma unroll
    for (int off = 1; off < 64; off <<= 1) {
        sum += __shfl_xor(sum, off, 64);
        sq  += __shfl_xor(sq, off, 64);
    }
    __shared__ float red[8];
    int w = tid >> 6, lane = tid & 63;
    if (lane == 0) { red[w] = sum; red[4 + w] = sq; }
    __syncthreads();
    sum = red[0] + red[1] + red[2] + red[3];
    sq  = red[4] + red[5] + red[6] + red[7];
    float mu = sum * (1.0f / DMODEL);
    float var = sq * (1.0f / DMODEL) - mu * mu;
    float rstd = rsqrtf(var + 1e-5f);
    float4 gv = *(const float4*)(g + tid * 4);
    float4 bv = *(const float4*)(b + tid * 4);
    ushort4 o;
    o.x = f2bf((v.x - mu) * rstd * gv.x + bv.x);
    o.y = f2bf((v.y - mu) * rstd * gv.y + bv.y);
    o.z = f2bf((v.z - mu) * rstd * gv.z + bv.z);
    o.w = f2bf((v.w - mu) * rstd * gv.w + bv.w);
    *(ushort4*)(out + (u64)row * DMODEL + tid * 4) = o;
}

// ---------------- bf16 MFMA GEMM: C[M][ldc] = A(grouped rows)[M][1024] @ Bt[N][1024]^T ----------------
template <typename OUT_T>
__global__ __launch_bounds__(256) void gemm_bf16(const u16* __restrict__ A,
                                                 const u16* __restrict__ Bt,
                                                 OUT_T* __restrict__ C,
                                                 int M, int ldc,
                                                 int rpgL2, long long gstride, float scale) {
    constexpr int K = 1024;
    __shared__ u16 As[128 * 32];
    __shared__ u16 Bs[128 * 32];
    int tid = threadIdx.x;
    int lane = tid & 63;
    int w = tid >> 6;
    int wm = w >> 1, wn = w & 1;
    // T1 XCD swizzle on the flattened block id
    int nwg = gridDim.x * gridDim.y;
    int wg = xcd_swizzle(blockIdx.y * gridDim.x + blockIdx.x, nwg);
    int m0 = (wg / gridDim.x) * 128;
    int n0 = (wg % gridDim.x) * 128;
    u32 rmask = (1u << rpgL2) - 1u;

    f32x4 acc[4][4] = {};

    for (int k0 = 0; k0 < K; k0 += 32) {
        __syncthreads();
#pragma unroll
        for (int i = 0; i < 2; ++i) {
            int t = i * 256 + tid;
            int r = t >> 2;
            int cg = t & 3;
            int col = (cg ^ ((r >> 1) & 3)) << 3;     // XOR-swizzled source column (T2 both-sides)
            int grow = m0 + r; if (grow >= M) grow = M - 1;
            const u16* ga = A + (u64)(grow >> rpgL2) * (u64)gstride + (u64)(grow & rmask) * K + k0 + col;
            __builtin_amdgcn_global_load_lds((const as1_u32*)ga,
                (as3_u32*)(As + ((i * 256 + (w << 6)) << 3)), 16, 0, 0);
            const u16* gb = Bt + (u64)(n0 + r) * K + k0 + col;
            __builtin_amdgcn_global_load_lds((const as1_u32*)gb,
                (as3_u32*)(Bs + ((i * 256 + (w << 6)) << 3)), 16, 0, 0);
        }
        __syncthreads();
        bf16x8 a[4], b[4];
        int rl = lane & 15;
        int cgl = lane >> 4;
#pragma unroll
        for (int mi = 0; mi < 4; ++mi) {
            int r = wm * 64 + mi * 16 + rl;
            int c = (cgl ^ ((r >> 1) & 3)) << 3;
            a[mi] = *(const bf16x8*)(As + r * 32 + c);
        }
#pragma unroll
        for (int ni = 0; ni < 4; ++ni) {
            int r = wn * 64 + ni * 16 + rl;
            int c = (cgl ^ ((r >> 1) & 3)) << 3;
            b[ni] = *(const bf16x8*)(Bs + r * 32 + c);
        }
#pragma unroll
        for (int mi = 0; mi < 4; ++mi)
#pragma unroll
            for (int ni = 0; ni < 4; ++ni)
                acc[mi][ni] = __builtin_amdgcn_mfma_f32_16x16x32_bf16(a[mi], b[ni], acc[mi][ni], 0, 0, 0);
    }
    // epilogue: C/D layout col = lane&15, row = (lane>>4)*4 + reg  [m89-verified]
    int rl = lane & 15, rg = lane >> 4;
#pragma unroll
    for (int mi = 0; mi < 4; ++mi) {
#pragma unroll
        for (int r = 0; r < 4; ++r) {
            int grow = m0 + wm * 64 + mi * 16 + rg * 4 + r;
            if (grow < M) {
#pragma unroll
                for (int ni = 0; ni < 4; ++ni) {
                    int gcol = n0 + wn * 64 + ni * 16 + rl;
                    float val = acc[mi][ni][r] * scale;
                    if constexpr (sizeof(OUT_T) == 2)
                        C[(u64)grow * ldc + gcol] = (OUT_T)f2bf(val);
                    else
                        C[(u64)grow * ldc + gcol] = val;
                }
            }
        }
    }
}

// ---------------- fused flash attention per (head, bt) ----------------
__global__ __launch_bounds__(256) void attn_kernel(const u16* __restrict__ qb,
                                                   const u16* __restrict__ kvb,
                                                   const int* __restrict__ mask,
                                                   u16* __restrict__ ob, int bt0) {
    int h = blockIdx.x;
    int btl = blockIdx.y;
    int tid = threadIdx.x, lane = tid & 63, w = tid >> 6;
    __shared__ u16 Ks[64 * 64];      // [kv][dh] XOR-swizzled (B^T layout for QK^T)
    __shared__ u16 Vt[64 * 64];      // [dh][kv] XOR-swizzled (B^T layout for PV)
    __shared__ u16 Ps[4][16 * 64];   // per-wave P, [q][kv] XOR-swizzled
    __shared__ float bias_s[64];

    bf16x8 aq[2];
    {
        int qr = btl * 64 + w * 16 + (lane & 15);
        const u16* qp = qb + (u64)qr * INNER_ + h * 64 + (lane >> 4) * 8;
        aq[0] = *(const bf16x8*)(qp);
        aq[1] = *(const bf16x8*)(qp + 32);
    }
    f32x4 acc[4] = {};
    float mrow[4], lrow[4];
#pragma unroll
    for (int r = 0; r < 4; ++r) { mrow[r] = -1e30f; lrow[r] = 0.f; }

    const u16* kvbase = kvb + (u64)btl * SEQ * KV_W;
    int rl = lane & 15, cgl = lane >> 4;

    for (int c = 0; c < SEQ / 64; ++c) {
        __syncthreads();
        // stage K chunk (pre-swizzled global source -> linear LDS dest)
#pragma unroll
        for (int i = 0; i < 2; ++i) {
            int t = i * 256 + tid;
            int r = t >> 3;
            int cgp = t & 7;
            int col = (cgp ^ (r & 7)) << 3;
            const u16* gk = kvbase + (u64)(c * 64 + r) * KV_W + h * 64 + col;
            __builtin_amdgcn_global_load_lds((const as1_u32*)gk,
                (as3_u32*)(Ks + ((i * 256 + (w << 6)) << 3)), 16, 0, 0);
        }
        // stage V transposed (manual, swizzled)
#pragma unroll
        for (int i = 0; i < 2; ++i) {
            int t = i * 256 + tid;
            int kvr = t >> 3;
            int d0 = (t & 7) << 3;
            const u16* gv = kvbase + (u64)(c * 64 + kvr) * KV_W + INNER_ + h * 64 + d0;
            ushort4 v0 = *(const ushort4*)gv;
            ushort4 v1 = *(const ushort4*)(gv + 4);
            u16 vals[8] = {v0.x, v0.y, v0.z, v0.w, v1.x, v1.y, v1.z, v1.w};
#pragma unroll
            for (int j = 0; j < 8; ++j) {
                int d = d0 + j;
                int cs = (((kvr >> 3) ^ (d & 7)) << 3) + (kvr & 7);
                Vt[d * 64 + cs] = vals[j];
            }
        }
        if (tid < 64) {
            int pos = c * 64 + tid;
            float bsv = 0.f;
            if (pos < NCTX) bsv = (mask[(bt0 + btl) * NCTX + pos] > 0) ? 0.f : -1e30f;
            bias_s[tid] = bsv;
        }
        __syncthreads();

        // S = q @ K^T (16 x 64), C-layout: row(q)=cgl*4+reg, col(kv)=ni*16+rl
        f32x4 sf[4];
#pragma unroll
        for (int ni = 0; ni < 4; ++ni) {
            f32x4 z = {};
#pragma unroll
            for (int kk = 0; kk < 2; ++kk) {
                int r = ni * 16 + rl;
                int cc = (((kk * 4 + cgl) ^ (r & 7)) << 3);
                bf16x8 bk = *(const bf16x8*)(Ks + r * 64 + cc);
                z = __builtin_amdgcn_mfma_f32_16x16x32_bf16(aq[kk], bk, z, 0, 0, 0);
            }
            float bias = bias_s[ni * 16 + rl];
            z[0] += bias; z[1] += bias; z[2] += bias; z[3] += bias;
            sf[ni] = z;
        }
        // online softmax
        float alpha[4];
#pragma unroll
        for (int r = 0; r < 4; ++r) {
            float m = fmaxf(fmaxf(sf[0][r], sf[1][r]), fmaxf(sf[2][r], sf[3][r]));
            m = fmaxf(m, __shfl_xor(m, 1, 64));
            m = fmaxf(m, __shfl_xor(m, 2, 64));
            m = fmaxf(m, __shfl_xor(m, 4, 64));
            m = fmaxf(m, __shfl_xor(m, 8, 64));
            float mn = fmaxf(mrow[r], m);
            alpha[r] = __expf(mrow[r] - mn);
            mrow[r] = mn;
        }
#pragma unroll
        for (int ni = 0; ni < 4; ++ni)
#pragma unroll
            for (int r = 0; r < 4; ++r)
                sf[ni][r] = __expf(sf[ni][r] - mrow[r]);
#pragma unroll
        for (int r = 0; r < 4; ++r) {
            float s = sf[0][r] + sf[1][r] + sf[2][r] + sf[3][r];
            s += __shfl_xor(s, 1, 64);
            s += __shfl_xor(s, 2, 64);
            s += __shfl_xor(s, 4, 64);
            s += __shfl_xor(s, 8, 64);
            lrow[r] = lrow[r] * alpha[r] + s;
        }
        // P -> per-wave LDS (bf16, swizzled)
        u16* pw = Ps[w];
#pragma unroll
        for (int ni = 0; ni < 4; ++ni) {
#pragma unroll
            for (int r = 0; r < 4; ++r) {
                int qrow = cgl * 4 + r;
                int kcol = ni * 16 + rl;
                int cs = (((kcol >> 3) ^ (qrow & 7)) << 3) + (kcol & 7);
                pw[qrow * 64 + cs] = f2bf(sf[ni][r]);
            }
        }
#pragma unroll
        for (int oi = 0; oi < 4; ++oi)
#pragma unroll
            for (int r = 0; r < 4; ++r)
                acc[oi][r] *= alpha[r];
        // PV
        bf16x8 ap[2];
#pragma unroll
        for (int kk = 0; kk < 2; ++kk) {
            int cc = (((kk * 4 + cgl) ^ (rl & 7)) << 3);
            ap[kk] = *(const bf16x8*)(pw + rl * 64 + cc);
        }
#pragma unroll
        for (int oi = 0; oi < 4; ++oi) {
#pragma unroll
            for (int kk = 0; kk < 2; ++kk) {
                int r = oi * 16 + rl;
                int cc = (((kk * 4 + cgl) ^ (r & 7)) << 3);
                bf16x8 bv = *(const bf16x8*)(Vt + r * 64 + cc);
                acc[oi] = __builtin_amdgcn_mfma_f32_16x16x32_bf16(ap[kk], bv, acc[oi], 0, 0, 0);
            }
        }
    }
    // epilogue
#pragma unroll
    for (int r = 0; r < 4; ++r) {
        float inv = 1.0f / lrow[r];
        int qrow = btl * 64 + w * 16 + cgl * 4 + r;
        u16* op = ob + (u64)qrow * INNER_ + h * 64;
#pragma unroll
        for (int oi = 0; oi < 4; ++oi)
            op[oi * 16 + rl] = f2bf(acc[oi][r] * inv);
    }
}

// ---------------- host ----------------
extern "C" void kernel_launch(void* const* d_in, const int* in_sizes, int n_in,
                              void* d_out, int out_size, void* d_ws, size_t ws_size,
                              hipStream_t stream) {
    const float* x    = (const float*)d_in[0];
    const float* lat  = (const float*)d_in[1];
    const int*   am   = (const int*)d_in[2];
    const float* gm   = (const float*)d_in[3];
    const float* bm   = (const float*)d_in[4];
    const float* gl   = (const float*)d_in[5];
    const float* bl   = (const float*)d_in[6];
    const float* Wq   = (const float*)d_in[7];
    const float* Wkv  = (const float*)d_in[8];
    const float* Wo   = (const float*)d_in[9];
    float* out = (float*)d_out;

    u16* WqT  = (u16*)d_ws;                       // [1024][1024]
    u16* WkvT = WqT + 1024 * 1024;                // [2048][1024]
    u16* WoT  = WkvT + 2048 * 1024;               // [1024][1024]
    u16* bufs = WoT + 1024 * 1024;

    size_t fixed = (size_t)(1024 * 1024 + 2048 * 1024 + 1024 * 1024) * 2;
    size_t perbt = (size_t)(SEQ * DMODEL + SEQ * KV_W + MLAT * DMODEL + MLAT * DMODEL) * 2;
    int C = 64;
    while (C > 1 && fixed + (size_t)C * perbt > ws_size) C >>= 1;

    transpose_cast<<<dim3(16, 16), 256, 0, stream>>>(Wq, WqT, 1024, 1024);
    transpose_cast<<<dim3(32, 16), 256, 0, stream>>>(Wkv, WkvT, 1024, 2048);
    transpose_cast<<<dim3(16, 16), 256, 0, stream>>>(Wo, WoT, 1024, 1024);

    for (int bt0 = 0; bt0 < 64; bt0 += C) {
        u16* xn = bufs;
        u16* kv = xn + (size_t)C * SEQ * DMODEL;
        u16* qb = kv + (size_t)C * SEQ * KV_W;
        u16* ao = qb + (size_t)C * MLAT * DMODEL;

        ln_cast<<<C * SEQ, 256, 0, stream>>>(x + (u64)bt0 * NCTX * DMODEL,
                                             lat + (u64)bt0 * MLAT * DMODEL,
                                             gm, bm, gl, bl, xn);
        // kv = xn @ Wkv   (contiguous rows)
        gemm_bf16<u16><<<dim3(KV_W / 128, (C * SEQ) / 128), 256, 0, stream>>>(
            xn, WkvT, kv, C * SEQ, KV_W, 30, 0, 1.0f);
        // q = ln @ Wq * 1/8  (latent rows: groups of 64 every 640)
        gemm_bf16<u16><<<dim3(INNER_ / 128, (C * MLAT + 127) / 128), 256, 0, stream>>>(
            xn + NCTX * DMODEL, WqT, qb, C * MLAT, INNER_, 6, (long long)SEQ * DMODEL, 0.125f);
        attn_kernel<<<dim3(NH, C), 256, 0, stream>>>(qb, kv, am, ao, bt0);
        // out = ao @ Wo  -> f32
        gemm_bf16<float><<<dim3(DMODEL / 128, (C * MLAT + 127) / 128), 256, 0, stream>>>(
            ao, WoT, out + (u64)bt0 * MLAT * DMODEL, C * MLAT, DMODEL, 30, 0, 1.0f);
    }
}